// Round 2
// baseline (1786.139 us; speedup 1.0000x reference)
//
#include <hip/hip_runtime.h>
#include <stdint.h>

#define B_SZ 4
#define LSEQ 4096
#define DMODEL 768
#define DSTATE 128
#define HEADD 64
#define DINNER 1536
#define NH 24
#define NPROJ 3352
#define NPROJ_PAD 3456
#define NXBC 1920            // xbcdt buffer width = NPROJ_PAD - DINNER
#define ROWS (B_SZ*LSEQ)     // 16384
#define QCH 512              // scan chunk length
#define NCH (LSEQ/QCH)       // 8

typedef __attribute__((ext_vector_type(8))) short short8;
typedef __attribute__((ext_vector_type(4))) float floatx4;

__device__ __forceinline__ unsigned short f2bf(float f){
  union { float f; unsigned u; } v; v.f = f;
  unsigned r = v.u + 0x7FFFu + ((v.u >> 16) & 1u);
  return (unsigned short)(r >> 16);
}
__device__ __forceinline__ float bf2f(unsigned short u){
  union { unsigned u; float f; } v; v.u = ((unsigned)u) << 16; return v.f;
}
__device__ __forceinline__ float silu(float v){ return v / (1.f + __expf(-v)); }

// ---------------- transpose fp32 src[R][C] -> bf16 dst[n][k]=src[k][n], zero-pad n>=C
__global__ __launch_bounds__(256) void transpose_bf16(const float* __restrict__ src, int R, int C,
                                                      unsigned short* __restrict__ dst){
  __shared__ __align__(16) float tile[32][33];
  int tx = threadIdx.x & 31, ty = threadIdx.x >> 5;   // 32 x 8
  int n0 = blockIdx.x * 32, k0 = blockIdx.y * 32;
  #pragma unroll
  for (int i = 0; i < 4; i++){
    int k = k0 + ty + i*8, n = n0 + tx;
    tile[ty + i*8][tx] = (n < C) ? src[(size_t)k * C + n] : 0.f;
  }
  __syncthreads();
  #pragma unroll
  for (int i = 0; i < 4; i++){
    int n = n0 + ty + i*8, k = k0 + tx;
    dst[(size_t)n * R + k] = f2bf(tile[tx][ty + i*8]);
  }
}

// ---------------- layernorm: x fp32 [ROWS][768] -> u bf16 ----------------
__global__ __launch_bounds__(256) void ln_kernel(const float* __restrict__ x, const float* __restrict__ w,
                                                 const float* __restrict__ b, unsigned short* __restrict__ u){
  int row = blockIdx.x, t = threadIdx.x;
  const float* xr = x + (size_t)row * DMODEL;
  float v0 = xr[t], v1 = xr[t+256], v2 = xr[t+512];
  float s = v0+v1+v2, ss = v0*v0+v1*v1+v2*v2;
  __shared__ float sa[4], sb[4];
  #pragma unroll
  for (int o = 32; o > 0; o >>= 1){ s += __shfl_down(s,o,64); ss += __shfl_down(ss,o,64); }
  if ((t & 63) == 0){ sa[t>>6] = s; sb[t>>6] = ss; }
  __syncthreads();
  s = sa[0]+sa[1]+sa[2]+sa[3]; ss = sb[0]+sb[1]+sb[2]+sb[3];
  float mu = s * (1.f/DMODEL);
  float var = ss * (1.f/DMODEL) - mu*mu;
  float rs = rsqrtf(var + 1e-5f);
  unsigned short* ur = u + (size_t)row * DMODEL;
  ur[t]     = f2bf((v0-mu)*rs*w[t]     + b[t]);
  ur[t+256] = f2bf((v1-mu)*rs*w[t+256] + b[t+256]);
  ur[t+512] = f2bf((v2-mu)*rs*w[t+512] + b[t+512]);
}

// ============ shared MFMA GEMM core (128x128 tile, 4 waves, 16x16x32 bf16) ============
#define SSTR 1040   // LDS seg stride (shorts): 128*8 + 8
#define GEMM_CORE(A_, Bt_, K_)                                                          \
  __shared__ __align__(16) short As[4*SSTR];                                            \
  __shared__ __align__(16) short Bs[4*SSTR];                                            \
  int t = threadIdx.x;                                                                  \
  int bm = blockIdx.y, bn = blockIdx.x;                                                 \
  int wave = t >> 6, lane = t & 63;                                                     \
  int wr = wave >> 1, wc = wave & 1;                                                    \
  int q = lane >> 4, m16 = lane & 15;                                                   \
  floatx4 acc[4][4];                                                                    \
  _Pragma("unroll") for (int i=0;i<4;i++)                                               \
    _Pragma("unroll") for (int j=0;j<4;j++) acc[i][j] = (floatx4){0.f,0.f,0.f,0.f};     \
  const int r0 = t >> 2, s0 = t & 3;                                                    \
  for (int kt = 0; kt < (K_); kt += 32){                                                \
    uint4 av0 = *(const uint4*)((A_)  + (size_t)(bm*128 + r0     )*(K_) + kt + s0*8);   \
    uint4 av1 = *(const uint4*)((A_)  + (size_t)(bm*128 + r0 + 64)*(K_) + kt + s0*8);   \
    uint4 bv0 = *(const uint4*)((Bt_) + (size_t)(bn*128 + r0     )*(K_) + kt + s0*8);   \
    uint4 bv1 = *(const uint4*)((Bt_) + (size_t)(bn*128 + r0 + 64)*(K_) + kt + s0*8);   \
    *(uint4*)(As + s0*SSTR + r0*8)      = av0;                                          \
    *(uint4*)(As + s0*SSTR + (r0+64)*8) = av1;                                          \
    *(uint4*)(Bs + s0*SSTR + r0*8)      = bv0;                                          \
    *(uint4*)(Bs + s0*SSTR + (r0+64)*8) = bv1;                                          \
    __syncthreads();                                                                    \
    short8 af[4], bf_[4];                                                               \
    _Pragma("unroll") for (int i=0;i<4;i++){                                            \
      af[i]  = *(const short8*)(As + q*SSTR + (wr*64 + i*16 + m16)*8);                  \
      bf_[i] = *(const short8*)(Bs + q*SSTR + (wc*64 + i*16 + m16)*8);                  \
    }                                                                                   \
    _Pragma("unroll") for (int i=0;i<4;i++)                                             \
      _Pragma("unroll") for (int j=0;j<4;j++)                                           \
        acc[i][j] = __builtin_amdgcn_mfma_f32_16x16x32_bf16(af[i], bf_[j], acc[i][j], 0, 0, 0); \
    __syncthreads();                                                                    \
  }

// ---------------- GEMM1: u[ROWS][768] x winT[3456][768]^T -> split bf16 epilogue -----
__global__ __launch_bounds__(256) void gemm_in(const short* __restrict__ A, const short* __restrict__ Bt,
                                               unsigned short* __restrict__ zb, unsigned short* __restrict__ xb,
                                               float* __restrict__ dtraw){
  GEMM_CORE(A, Bt, DMODEL)
  #pragma unroll
  for (int i=0;i<4;i++){
    int grow_base = bm*128 + wr*64 + i*16 + q*4;
    #pragma unroll
    for (int j=0;j<4;j++){
      int gcol = bn*128 + wc*64 + j*16 + m16;
      #pragma unroll
      for (int r=0;r<4;r++){
        int row = grow_base + r;
        float v = acc[i][j][r];
        if (gcol < DINNER){
          zb[(size_t)row*DINNER + gcol] = f2bf(v);
        } else {
          xb[(size_t)row*NXBC + (gcol - DINNER)] = f2bf(v);
          if (gcol >= (NPROJ-NH) && gcol < NPROJ)
            dtraw[(size_t)row*NH + (gcol - (NPROJ-NH))] = v;
        }
      }
    }
  }
}

// ---------------- GEMM2: generic fp32 out + residual ----------------
__global__ __launch_bounds__(256) void gemm_out(const short* __restrict__ A, const short* __restrict__ Bt,
                                                float* __restrict__ C, const float* __restrict__ resid){
  GEMM_CORE(A, Bt, DINNER)
  #pragma unroll
  for (int i=0;i<4;i++){
    int grow_base = bm*128 + wr*64 + i*16 + q*4;
    #pragma unroll
    for (int j=0;j<4;j++){
      int gcol = bn*128 + wc*64 + j*16 + m16;
      #pragma unroll
      for (int r=0;r<4;r++){
        size_t idx = (size_t)(grow_base + r) * DMODEL + gcol;
        C[idx] = acc[i][j][r] + resid[idx];
      }
    }
  }
}

// ---------------- dt: softplus + dA (fp32 input) ----------------
__global__ void dt_kernel(const float* __restrict__ dtraw, const float* __restrict__ dt_bias,
                          const float* __restrict__ A_log, float* __restrict__ dtb, float* __restrict__ dab){
  int id = blockIdx.x*256 + threadIdx.x;
  if (id >= ROWS*NH) return;
  int h = id % NH;
  float xr = dtraw[id] + dt_bias[h];
  float dt = (xr > 20.f) ? xr : log1pf(expf(xr));
  float A = -expf(A_log[h]);
  dtb[id] = dt;
  dab[id] = expf(dt*A);
}

// ---------------- scan pass A: fused conv+silu, per-chunk local state sums -----------
__global__ __launch_bounds__(512) void scan_partial(const unsigned short* __restrict__ xbc,
                                                    const float* __restrict__ dtb, const float* __restrict__ dab,
                                                    const float* __restrict__ cw, const float* __restrict__ cb,
                                                    float* __restrict__ cstate, float* __restrict__ Pbuf){
  int bid = blockIdx.x;               // b*NH*NCH + h*NCH + c
  int c = bid & (NCH-1), h = (bid / NCH) % NH, b = bid / (NH*NCH);
  int t = threadIdx.x;
  int p = t >> 3, n0 = (t & 7) * 16;
  __shared__ __align__(16) float sB[DSTATE];
  __shared__ __align__(16) float sX[HEADD];
  __shared__ float sS[2];
  bool owner = (t < 192);
  int ch = (t < 128) ? (DINNER + t) : (h*HEADD + (t-128));   // conv channel == xbc col
  float w0=0,w1=0,w2=0,w3=0,bias=0, ra=0,rb=0,rc=0,rd=0;
  int l0 = c*QCH;
  size_t rowbase = (size_t)(b*LSEQ + l0) * NXBC;
  if (owner){
    w0=cw[ch*4]; w1=cw[ch*4+1]; w2=cw[ch*4+2]; w3=cw[ch*4+3]; bias=cb[ch];
    if (l0 >= 1) rc = bf2f(xbc[rowbase -   NXBC + ch]);
    if (l0 >= 2) rb = bf2f(xbc[rowbase - 2*NXBC + ch]);
    if (l0 >= 3) ra = bf2f(xbc[rowbase - 3*NXBC + ch]);
    rd = bf2f(xbc[rowbase + ch]);
  }
  float sc_a=0, sc_d=0;
  if (t == 192){ int idx=(b*LSEQ+l0)*NH + h; sc_a = dab[idx]; sc_d = dtb[idx]; }
  float s[16];
  #pragma unroll
  for (int i=0;i<16;i++) s[i] = 0.f;
  float prodA = 1.f;
  for (int tau = 0; tau < QCH; tau++){
    float rnext=0, na=0, nd=0;
    if (tau+1 < QCH){
      if (owner) rnext = bf2f(xbc[rowbase + (size_t)(tau+1)*NXBC + ch]);
      if (t==192){ int idx=(b*LSEQ+l0+tau+1)*NH + h; na=dab[idx]; nd=dtb[idx]; }
    }
    if (owner){
      float v = silu(bias + w0*ra + w1*rb + w2*rc + w3*rd);
      if (t < 128) sB[t] = v; else sX[t-128] = v;
    }
    if (t==192){ sS[0]=sc_a; sS[1]=sc_d; }
    __syncthreads();
    float a = sS[0];
    float coef = sS[1] * sX[p];
    prodA *= a;
    const float4* B4 = (const float4*)(sB + n0);
    #pragma unroll
    for (int qq=0;qq<4;qq++){
      float4 bv = B4[qq];
      s[qq*4+0] = fmaf(a, s[qq*4+0], coef*bv.x);
      s[qq*4+1] = fmaf(a, s[qq*4+1], coef*bv.y);
      s[qq*4+2] = fmaf(a, s[qq*4+2], coef*bv.z);
      s[qq*4+3] = fmaf(a, s[qq*4+3], coef*bv.w);
    }
    __syncthreads();
    ra=rb; rb=rc; rc=rd; rd=rnext;
    sc_a=na; sc_d=nd;
  }
  size_t outb = (size_t)bid*8192 + p*128 + n0;
  #pragma unroll
  for (int qq=0;qq<4;qq++)
    *(float4*)(cstate + outb + qq*4) = (float4){ s[qq*4+0], s[qq*4+1], s[qq*4+2], s[qq*4+3] };
  if (t == 0) Pbuf[bid] = prodA;
}

// ---------------- scan pass B: sequential chunk combine -> init states ----------------
__global__ __launch_bounds__(512) void scan_combine(float* __restrict__ cstate, const float* __restrict__ Pbuf){
  int bh = blockIdx.x;   // b*NH + h
  int t = threadIdx.x;
  size_t off = (size_t)(t >> 3)*128 + (t & 7)*16;
  float hrun[16];
  #pragma unroll
  for (int i=0;i<16;i++) hrun[i] = 0.f;
  for (int c = 0; c < NCH; c++){
    float4* ptr = (float4*)(cstate + (size_t)(bh*NCH + c)*8192 + off);
    float P = Pbuf[bh*NCH + c];
    #pragma unroll
    for (int qq=0;qq<4;qq++){
      float4 v = ptr[qq];  // local sum Sc
      float4 hv = { hrun[qq*4+0], hrun[qq*4+1], hrun[qq*4+2], hrun[qq*4+3] };
      ptr[qq] = hv;        // overwrite with init state for this chunk
      hrun[qq*4+0] = fmaf(P, hrun[qq*4+0], v.x);
      hrun[qq*4+1] = fmaf(P, hrun[qq*4+1], v.y);
      hrun[qq*4+2] = fmaf(P, hrun[qq*4+2], v.z);
      hrun[qq*4+3] = fmaf(P, hrun[qq*4+3], v.w);
    }
  }
}

// ---------------- scan pass C: fused conv+silu, replay from init state, emit y (bf16) -
__global__ __launch_bounds__(512) void scan_apply(const unsigned short* __restrict__ xbc,
                                                  const float* __restrict__ dtb, const float* __restrict__ dab,
                                                  const float* __restrict__ cw, const float* __restrict__ cb,
                                                  const float* __restrict__ cstate, const float* __restrict__ Dp,
                                                  unsigned short* __restrict__ yb){
  int bid = blockIdx.x;
  int c = bid & (NCH-1), h = (bid / NCH) % NH, b = bid / (NH*NCH);
  int t = threadIdx.x;
  int p = t >> 3, n0 = (t & 7) * 16;
  __shared__ __align__(16) float sB[DSTATE];
  __shared__ __align__(16) float sC[DSTATE];
  __shared__ __align__(16) float sX[HEADD];
  __shared__ float sS[2];
  bool owner = (t < 320);
  int ch = (t < 128) ? (DINNER + t) : ((t < 192) ? (h*HEADD + (t-128)) : (DINNER + DSTATE + (t-192)));
  float w0=0,w1=0,w2=0,w3=0,bias=0, ra=0,rb=0,rc=0,rd=0;
  int l0 = c*QCH;
  size_t rowbase = (size_t)(b*LSEQ + l0) * NXBC;
  if (owner){
    w0=cw[ch*4]; w1=cw[ch*4+1]; w2=cw[ch*4+2]; w3=cw[ch*4+3]; bias=cb[ch];
    if (l0 >= 1) rc = bf2f(xbc[rowbase -   NXBC + ch]);
    if (l0 >= 2) rb = bf2f(xbc[rowbase - 2*NXBC + ch]);
    if (l0 >= 3) ra = bf2f(xbc[rowbase - 3*NXBC + ch]);
    rd = bf2f(xbc[rowbase + ch]);
  }
  float sc_a=0, sc_d=0;
  if (t == 320){ int idx=(b*LSEQ+l0)*NH + h; sc_a = dab[idx]; sc_d = dtb[idx]; }
  float s[16];
  {
    size_t inb = (size_t)bid*8192 + p*128 + n0;
    #pragma unroll
    for (int qq=0;qq<4;qq++){
      float4 v = *(const float4*)(cstate + inb + qq*4);
      s[qq*4+0]=v.x; s[qq*4+1]=v.y; s[qq*4+2]=v.z; s[qq*4+3]=v.w;
    }
  }
  float Dh = Dp[h];
  for (int tau = 0; tau < QCH; tau++){
    int bl = b*LSEQ + l0 + tau;
    float rnext=0, na=0, nd=0;
    if (tau+1 < QCH){
      if (owner) rnext = bf2f(xbc[rowbase + (size_t)(tau+1)*NXBC + ch]);
      if (t==320){ int idx=(bl+1)*NH + h; na=dab[idx]; nd=dtb[idx]; }
    }
    if (owner){
      float v = silu(bias + w0*ra + w1*rb + w2*rc + w3*rd);
      if (t < 128) sB[t] = v;
      else if (t < 192) sX[t-128] = v;
      else sC[t-192] = v;
    }
    if (t==320){ sS[0]=sc_a; sS[1]=sc_d; }
    __syncthreads();
    float a = sS[0];
    float sXp = sX[p];
    float coef = sS[1] * sXp;
    const float4* B4 = (const float4*)(sB + n0);
    const float4* C4 = (const float4*)(sC + n0);
    float part = 0.f;
    #pragma unroll
    for (int qq=0;qq<4;qq++){
      float4 bv = B4[qq];
      float4 cv = C4[qq];
      s[qq*4+0] = fmaf(a, s[qq*4+0], coef*bv.x);
      s[qq*4+1] = fmaf(a, s[qq*4+1], coef*bv.y);
      s[qq*4+2] = fmaf(a, s[qq*4+2], coef*bv.z);
      s[qq*4+3] = fmaf(a, s[qq*4+3], coef*bv.w);
      part += s[qq*4+0]*cv.x + s[qq*4+1]*cv.y + s[qq*4+2]*cv.z + s[qq*4+3]*cv.w;
    }
    part += __shfl_xor(part, 1, 64);
    part += __shfl_xor(part, 2, 64);
    part += __shfl_xor(part, 4, 64);
    if ((t & 7) == 0)
      yb[(size_t)bl*DINNER + h*HEADD + p] = f2bf(part + Dh * sXp);
    __syncthreads();
    ra=rb; rb=rc; rc=rd; rd=rnext;
    sc_a=na; sc_d=nd;
  }
}

// ---------------- gate (silu(z)) + RMSNorm -> yn bf16 ----------------
__global__ __launch_bounds__(256) void gate_rms(const unsigned short* __restrict__ y,
                                                const unsigned short* __restrict__ z,
                                                const float* __restrict__ nw, unsigned short* __restrict__ yn){
  int row = blockIdx.x, t = threadIdx.x;
  const unsigned short* yr = y + (size_t)row*DINNER;
  const unsigned short* zr = z + (size_t)row*DINNER;
  float g[6]; float ss = 0.f;
  #pragma unroll
  for (int i=0;i<6;i++){
    int c2 = t + i*256;
    float zv = bf2f(zr[c2]);
    float gv = bf2f(yr[c2]) * silu(zv);
    g[i] = gv; ss += gv*gv;
  }
  __shared__ float sb_[4];
  #pragma unroll
  for (int o = 32; o > 0; o >>= 1) ss += __shfl_down(ss,o,64);
  if ((t & 63) == 0) sb_[t>>6] = ss;
  __syncthreads();
  ss = sb_[0]+sb_[1]+sb_[2]+sb_[3];
  float scale = rsqrtf(ss*(1.f/DINNER) + 1e-5f);
  unsigned short* ynr = yn + (size_t)row*DINNER;
  #pragma unroll
  for (int i=0;i<6;i++){
    int c2 = t + i*256;
    ynr[c2] = f2bf(g[i]*scale*nw[c2]);
  }
}

extern "C" void kernel_launch(void* const* d_in, const int* in_sizes, int n_in,
                              void* d_out, int out_size, void* d_ws, size_t ws_size,
                              hipStream_t stream){
  const float* x      = (const float*)d_in[0];
  const float* ln_w   = (const float*)d_in[1];
  const float* ln_b   = (const float*)d_in[2];
  const float* W_in   = (const float*)d_in[3];
  const float* conv_w = (const float*)d_in[4];
  const float* conv_b = (const float*)d_in[5];
  const float* A_log  = (const float*)d_in[6];
  const float* Dp     = (const float*)d_in[7];
  const float* dt_b   = (const float*)d_in[8];
  const float* nw     = (const float*)d_in[9];
  const float* W_out  = (const float*)d_in[10];
  float* out = (float*)d_out;

  char* ws = (char*)d_ws;
  size_t off = 0;
  auto alloc = [&](size_t bytes)->char*{ char* pp = ws + off; off += (bytes + 255) & ~(size_t)255; return pp; };
  // total address space ~201 MB (aliased lifetimes):
  unsigned short* zbuf  = (unsigned short*)alloc((size_t)ROWS*DINNER*2);   // 50.3 MB, live GEMM1..gate
  unsigned short* xbcdt = (unsigned short*)alloc((size_t)ROWS*NXBC*2);     // 62.9 MB, live GEMM1..scan_apply
  float* dtraw = (float*)alloc((size_t)ROWS*NH*4);                         // 1.6 MB
  float* dtb   = (float*)alloc((size_t)ROWS*NH*4);                         // 1.6 MB
  float* dab   = (float*)alloc((size_t)ROWS*NH*4);                         // 1.6 MB
  char* big0   = alloc((size_t)ROWS*DMODEL*2);                             // 25.2 MB: u_bf then cstate
  char* big1   = alloc((size_t)NPROJ_PAD*DMODEL*2);                        // 5.3 MB: winT then Pbuf
  unsigned short* ybuf = (unsigned short*)alloc((size_t)ROWS*DINNER*2);    // 50.3 MB
  unsigned short* woutT= (unsigned short*)alloc((size_t)DMODEL*DINNER*2);  // 2.4 MB
  unsigned short* u_bf = (unsigned short*)big0;       // dead after GEMM1
  float* cstate        = (float*)big0;                // B*NH*NCH*8192*4 = 25.2 MB, born scan_partial
  unsigned short* winT = (unsigned short*)big1;       // dead after GEMM1
  float* Pbuf          = (float*)big1;                // 3 KB, born scan_partial
  unsigned short* ynb  = xbcdt;                       // 50.3 MB <= 62.9 MB, born gate_rms
  (void)ws_size; (void)in_sizes; (void)n_in; (void)out_size;

  transpose_bf16<<<dim3(NPROJ_PAD/32, DMODEL/32), 256, 0, stream>>>(W_in, DMODEL, NPROJ, winT);
  transpose_bf16<<<dim3(DMODEL/32, DINNER/32), 256, 0, stream>>>(W_out, DINNER, DMODEL, woutT);
  ln_kernel<<<ROWS, 256, 0, stream>>>(x, ln_w, ln_b, u_bf);
  gemm_in<<<dim3(NPROJ_PAD/128, ROWS/128), 256, 0, stream>>>((const short*)u_bf, (const short*)winT,
                                                             zbuf, xbcdt, dtraw);
  dt_kernel<<<(ROWS*NH + 255)/256, 256, 0, stream>>>(dtraw, dt_b, A_log, dtb, dab);
  scan_partial<<<B_SZ*NH*NCH, 512, 0, stream>>>(xbcdt, dtb, dab, conv_w, conv_b, cstate, Pbuf);
  scan_combine<<<B_SZ*NH, 512, 0, stream>>>(cstate, Pbuf);
  scan_apply<<<B_SZ*NH*NCH, 512, 0, stream>>>(xbcdt, dtb, dab, conv_w, conv_b, cstate, Dp, ybuf);
  gate_rms<<<ROWS, 256, 0, stream>>>(ybuf, zbuf, nw, ynb);
  gemm_out<<<dim3(DMODEL/128, ROWS/128), 256, 0, stream>>>((const short*)ynb, (const short*)woutT,
                                                           out, x);
}

// Round 3
// 777.546 us; speedup vs baseline: 2.2971x; 2.2971x over previous
//
#include <hip/hip_runtime.h>
#include <stdint.h>

#define B_SZ 4
#define LSEQ 4096
#define DMODEL 768
#define DSTATE 128
#define HEADD 64
#define DINNER 1536
#define NH 24
#define NPROJ 3352
#define NPROJ_PAD 3456
#define NXBC 1920            // xbcdt buffer width = NPROJ_PAD - DINNER
#define ROWS (B_SZ*LSEQ)     // 16384
#define QC 64                // SSD chunk length
#define NCH (LSEQ/QC)        // 64 chunks

typedef __attribute__((ext_vector_type(8))) short short8;
typedef __attribute__((ext_vector_type(4))) float floatx4;

__device__ __forceinline__ unsigned short f2bf(float f){
  union { float f; unsigned u; } v; v.f = f;
  unsigned r = v.u + 0x7FFFu + ((v.u >> 16) & 1u);
  return (unsigned short)(r >> 16);
}
__device__ __forceinline__ float bf2f(unsigned short u){
  union { unsigned u; float f; } v; v.u = ((unsigned)u) << 16; return v.f;
}
__device__ __forceinline__ float silu(float v){ return v / (1.f + __expf(-v)); }

// ---------------- transpose fp32 src[R][C] -> bf16 dst[n][k]=src[k][n], zero-pad n>=C
__global__ __launch_bounds__(256) void transpose_bf16(const float* __restrict__ src, int R, int C,
                                                      unsigned short* __restrict__ dst){
  __shared__ __align__(16) float tile[32][33];
  int tx = threadIdx.x & 31, ty = threadIdx.x >> 5;   // 32 x 8
  int n0 = blockIdx.x * 32, k0 = blockIdx.y * 32;
  #pragma unroll
  for (int i = 0; i < 4; i++){
    int k = k0 + ty + i*8, n = n0 + tx;
    tile[ty + i*8][tx] = (n < C) ? src[(size_t)k * C + n] : 0.f;
  }
  __syncthreads();
  #pragma unroll
  for (int i = 0; i < 4; i++){
    int n = n0 + ty + i*8, k = k0 + tx;
    dst[(size_t)n * R + k] = f2bf(tile[tx][ty + i*8]);
  }
}

// ---------------- layernorm: x fp32 [ROWS][768] -> u bf16 ----------------
__global__ __launch_bounds__(256) void ln_kernel(const float* __restrict__ x, const float* __restrict__ w,
                                                 const float* __restrict__ b, unsigned short* __restrict__ u){
  int row = blockIdx.x, t = threadIdx.x;
  const float* xr = x + (size_t)row * DMODEL;
  float v0 = xr[t], v1 = xr[t+256], v2 = xr[t+512];
  float s = v0+v1+v2, ss = v0*v0+v1*v1+v2*v2;
  __shared__ float sa[4], sb[4];
  #pragma unroll
  for (int o = 32; o > 0; o >>= 1){ s += __shfl_down(s,o,64); ss += __shfl_down(ss,o,64); }
  if ((t & 63) == 0){ sa[t>>6] = s; sb[t>>6] = ss; }
  __syncthreads();
  s = sa[0]+sa[1]+sa[2]+sa[3]; ss = sb[0]+sb[1]+sb[2]+sb[3];
  float mu = s * (1.f/DMODEL);
  float var = ss * (1.f/DMODEL) - mu*mu;
  float rs = rsqrtf(var + 1e-5f);
  unsigned short* ur = u + (size_t)row * DMODEL;
  ur[t]     = f2bf((v0-mu)*rs*w[t]     + b[t]);
  ur[t+256] = f2bf((v1-mu)*rs*w[t+256] + b[t+256]);
  ur[t+512] = f2bf((v2-mu)*rs*w[t+512] + b[t+512]);
}

// ============ shared MFMA GEMM core (128x128 tile, 4 waves, 16x16x32 bf16) ============
#define SSTR 1040   // LDS seg stride (shorts): 128*8 + 8
#define GEMM_CORE(A_, Bt_, K_)                                                          \
  __shared__ __align__(16) short As[4*SSTR];                                            \
  __shared__ __align__(16) short Bs[4*SSTR];                                            \
  int t = threadIdx.x;                                                                  \
  int bm = blockIdx.y, bn = blockIdx.x;                                                 \
  int wave = t >> 6, lane = t & 63;                                                     \
  int wr = wave >> 1, wc = wave & 1;                                                    \
  int q = lane >> 4, m16 = lane & 15;                                                   \
  floatx4 acc[4][4];                                                                    \
  _Pragma("unroll") for (int i=0;i<4;i++)                                               \
    _Pragma("unroll") for (int j=0;j<4;j++) acc[i][j] = (floatx4){0.f,0.f,0.f,0.f};     \
  const int r0 = t >> 2, s0 = t & 3;                                                    \
  for (int kt = 0; kt < (K_); kt += 32){                                                \
    uint4 av0 = *(const uint4*)((A_)  + (size_t)(bm*128 + r0     )*(K_) + kt + s0*8);   \
    uint4 av1 = *(const uint4*)((A_)  + (size_t)(bm*128 + r0 + 64)*(K_) + kt + s0*8);   \
    uint4 bv0 = *(const uint4*)((Bt_) + (size_t)(bn*128 + r0     )*(K_) + kt + s0*8);   \
    uint4 bv1 = *(const uint4*)((Bt_) + (size_t)(bn*128 + r0 + 64)*(K_) + kt + s0*8);   \
    *(uint4*)(As + s0*SSTR + r0*8)      = av0;                                          \
    *(uint4*)(As + s0*SSTR + (r0+64)*8) = av1;                                          \
    *(uint4*)(Bs + s0*SSTR + r0*8)      = bv0;                                          \
    *(uint4*)(Bs + s0*SSTR + (r0+64)*8) = bv1;                                          \
    __syncthreads();                                                                    \
    short8 af[4], bf_[4];                                                               \
    _Pragma("unroll") for (int i=0;i<4;i++){                                            \
      af[i]  = *(const short8*)(As + q*SSTR + (wr*64 + i*16 + m16)*8);                  \
      bf_[i] = *(const short8*)(Bs + q*SSTR + (wc*64 + i*16 + m16)*8);                  \
    }                                                                                   \
    _Pragma("unroll") for (int i=0;i<4;i++)                                             \
      _Pragma("unroll") for (int j=0;j<4;j++)                                           \
        acc[i][j] = __builtin_amdgcn_mfma_f32_16x16x32_bf16(af[i], bf_[j], acc[i][j], 0, 0, 0); \
    __syncthreads();                                                                    \
  }

// ---------------- GEMM1: u[ROWS][768] x winT[3456][768]^T -> split bf16 epilogue -----
__global__ __launch_bounds__(256) void gemm_in(const short* __restrict__ A, const short* __restrict__ Bt,
                                               unsigned short* __restrict__ zb, unsigned short* __restrict__ xb,
                                               float* __restrict__ dtraw){
  GEMM_CORE(A, Bt, DMODEL)
  #pragma unroll
  for (int i=0;i<4;i++){
    int grow_base = bm*128 + wr*64 + i*16 + q*4;
    #pragma unroll
    for (int j=0;j<4;j++){
      int gcol = bn*128 + wc*64 + j*16 + m16;
      #pragma unroll
      for (int r=0;r<4;r++){
        int row = grow_base + r;
        float v = acc[i][j][r];
        if (gcol < DINNER){
          zb[(size_t)row*DINNER + gcol] = f2bf(v);
        } else {
          xb[(size_t)row*NXBC + (gcol - DINNER)] = f2bf(v);
          if (gcol >= (NPROJ-NH) && gcol < NPROJ)
            dtraw[(size_t)row*NH + (gcol - (NPROJ-NH))] = v;
        }
      }
    }
  }
}

// ---------------- GEMM2: generic fp32 out + residual ----------------
__global__ __launch_bounds__(256) void gemm_out(const short* __restrict__ A, const short* __restrict__ Bt,
                                                float* __restrict__ C, const float* __restrict__ resid){
  GEMM_CORE(A, Bt, DINNER)
  #pragma unroll
  for (int i=0;i<4;i++){
    int grow_base = bm*128 + wr*64 + i*16 + q*4;
    #pragma unroll
    for (int j=0;j<4;j++){
      int gcol = bn*128 + wc*64 + j*16 + m16;
      #pragma unroll
      for (int r=0;r<4;r++){
        size_t idx = (size_t)(grow_base + r) * DMODEL + gcol;
        C[idx] = acc[i][j][r] + resid[idx];
      }
    }
  }
}

// ---------------- dt: softplus -> dtb ----------------
__global__ void dt_kernel(const float* __restrict__ dtraw, const float* __restrict__ dt_bias,
                          float* __restrict__ dtb){
  int id = blockIdx.x*256 + threadIdx.x;
  if (id >= ROWS*NH) return;
  int h = id % NH;
  float xr = dtraw[id] + dt_bias[h];
  float dt = (xr > 20.f) ? xr : log1pf(expf(xr));
  dtb[id] = dt;
}

// ---------------- conv+silu for B,C channels only -> bcconv [ROWS][256] bf16 ---------
__global__ __launch_bounds__(256) void conv_bc(const unsigned short* __restrict__ xbc,
                                               const float* __restrict__ cw, const float* __restrict__ cb,
                                               unsigned short* __restrict__ bcv){
  int row = blockIdx.x, c = threadIdx.x;          // c = 0..255 (B: 0..127, C: 128..255)
  int l = row & (LSEQ-1);
  int chg = DINNER + c;                           // conv channel index
  float acc = cb[chg];
  #pragma unroll
  for (int k = 0; k < 4; k++){
    int ls = l + k - 3;
    if (ls >= 0) acc = fmaf(cw[chg*4+k], bf2f(xbc[(size_t)(row + k - 3)*NXBC + 1536 + c]), acc);
  }
  bcv[(size_t)row*256 + c] = f2bf(silu(acc));
}

// ---------------- SSD scan: grid (b*NH), 256 threads = 4 waves, 64 chunks of 64 -------
// Per chunk: G=C@B^T (MFMA), M=mask*exp(segsum)*dt*G, Y=M@X^T + diag(cum)*(C@h^T)+D*X,
// h <- P*h + (X^T*W)@B  (h carried in fp32 MFMA accumulators across chunks).
__global__ __launch_bounds__(256, 1) void ssd_scan(const unsigned short* __restrict__ xbc,
                                                   const unsigned short* __restrict__ bcv,
                                                   const float* __restrict__ dtb,
                                                   const float* __restrict__ cw, const float* __restrict__ cb,
                                                   const float* __restrict__ A_log, const float* __restrict__ Dp,
                                                   unsigned short* __restrict__ yb){
  __shared__ __align__(16) unsigned short sBl[QC][136];   // B [s][n]  (n=128, pad 8)
  __shared__ __align__(16) unsigned short sCl[QC][136];   // C [t][n]
  __shared__ __align__(16) unsigned short sXT[HEADD][72]; // X^T [p][s] (pad 8)
  __shared__ __align__(16) unsigned short sXW[HEADD][72]; // X^T * W [p][s]
  __shared__ __align__(16) unsigned short sM [QC][72];    // M [t][s]
  __shared__ __align__(16) unsigned short sH [HEADD][136];// h bf16 [p][n] (prev chunk)
  __shared__ __align__(16) unsigned short sRaw[67][72];   // raw X rows for conv
  __shared__ float sSeg[2][QC], sDt[2][QC], sW[2][QC], sCum[2][QC];

  int bid = blockIdx.x;
  int h = bid % NH, b = bid / NH;
  int bseq = b * LSEQ;
  int tid = threadIdx.x;
  int wv = tid >> 6, ln = tid & 63, q = ln >> 4, l16 = ln & 15;
  float A_h = -__expf(A_log[h]);
  float Dh = Dp[h];

  // conv weights for this thread's 4 X-channel slots (channel = (tid>>4) + 16*sl)
  float cwr[4][4], cbr[4];
  #pragma unroll
  for (int sl = 0; sl < 4; sl++){
    int chg = h*HEADD + (tid>>4) + 16*sl;
    #pragma unroll
    for (int k = 0; k < 4; k++) cwr[sl][k] = cw[chg*4+k];
    cbr[sl] = cb[chg];
  }

  // zero h (LDS) and h accumulators
  for (int i = tid; i < HEADD*136/2; i += 256) ((unsigned*)sH)[i] = 0u;
  floatx4 hacc[8];
  #pragma unroll
  for (int i = 0; i < 8; i++) hacc[i] = (floatx4){0.f,0.f,0.f,0.f};

  for (int c = 0; c < NCH; c++){
    int par = c & 1;
    int l0 = c * QC;
    // ---- phase 0: global loads + LDS staging + seg-scan (wave 0) ----
    {
      // B/C rows from bcconv: thread -> row tid>>2, 8 chan-groups
      int r = tid >> 2, gb = tid & 3;
      const unsigned short* bcrow = bcv + (size_t)(bseq + l0 + r)*256;
      uint4 bcl[8];
      #pragma unroll
      for (int j = 0; j < 8; j++) bcl[j] = *(const uint4*)(bcrow + (gb + 4*j)*8);
      // raw X rows l0-3 .. l0+63
      uint4 rxl[3]; int rrow[3], rg[3]; bool rv[3];
      #pragma unroll
      for (int j = 0; j < 3; j++){
        int idx = tid + 256*j;
        rv[j] = idx < 536;
        int rr = idx >> 3, g = idx & 7;
        rrow[j] = rr; rg[j] = g;
        rxl[j] = (uint4){0,0,0,0};
        if (rv[j]){
          int gl = l0 + rr - 3;
          if (gl >= 0) rxl[j] = *(const uint4*)(xbc + (size_t)(bseq + gl)*NXBC + h*HEADD + g*8);
        }
      }
      if (wv == 0){
        float dtv = dtb[(size_t)(bseq + l0 + ln)*NH + h];
        float sg = dtv * A_h;
        #pragma unroll
        for (int off = 1; off < 64; off <<= 1){
          float o = __shfl_up(sg, off, 64);
          sg += (ln >= off) ? o : 0.f;
        }
        float segLast = __shfl(sg, 63, 64);
        sSeg[par][ln] = sg; sDt[par][ln] = dtv;
        sW[par][ln] = dtv * __expf(segLast - sg);
        sCum[par][ln] = __expf(sg);
      }
      #pragma unroll
      for (int j = 0; j < 8; j++){
        int ch0 = (gb + 4*j) * 8;
        if (ch0 < 128) *(uint4*)&sBl[r][ch0] = bcl[j];
        else           *(uint4*)&sCl[r][ch0-128] = bcl[j];
      }
      #pragma unroll
      for (int j = 0; j < 3; j++)
        if (rv[j]) *(uint4*)&sRaw[rrow[j]][rg[j]*8] = rxl[j];
    }
    __syncthreads();
    // ---- phase 1: G MFMAs, X conv -> sXT/sXW, M write ----
    short8 cf[4];
    #pragma unroll
    for (int kt = 0; kt < 4; kt++) cf[kt] = *(const short8*)&sCl[16*wv + l16][kt*32 + q*8];
    floatx4 g[4];
    #pragma unroll
    for (int st = 0; st < 4; st++) g[st] = (floatx4){0.f,0.f,0.f,0.f};
    #pragma unroll
    for (int kt = 0; kt < 4; kt++){
      #pragma unroll
      for (int st = 0; st < 4; st++){
        short8 bfr = *(const short8*)&sBl[16*st + l16][kt*32 + q*8];
        g[st] = __builtin_amdgcn_mfma_f32_16x16x32_bf16(cf[kt], bfr, g[st], 0, 0, 0);
      }
    }
    // X depthwise conv + silu (slot: ch=(tid>>4)+16*sl, s-range (tid&15)*4..+3)
    {
      int s4 = (tid & 15) * 4;
      #pragma unroll
      for (int sl = 0; sl < 4; sl++){
        int ch = (tid >> 4) + 16*sl;
        float rr[7];
        #pragma unroll
        for (int k = 0; k < 7; k++) rr[k] = bf2f(sRaw[s4 + k][ch]);
        #pragma unroll
        for (int i = 0; i < 4; i++){
          float v = cbr[sl] + cwr[sl][0]*rr[i] + cwr[sl][1]*rr[i+1] + cwr[sl][2]*rr[i+2] + cwr[sl][3]*rr[i+3];
          v = silu(v);
          sXT[ch][s4+i] = f2bf(v);
          sXW[ch][s4+i] = f2bf(v * sW[par][s4+i]);
        }
      }
    }
    // M = mask * exp(seg[t]-seg[s]) * dt[s] * G
    #pragma unroll
    for (int st = 0; st < 4; st++){
      #pragma unroll
      for (int r = 0; r < 4; r++){
        int tt = 16*wv + q*4 + r;
        int ss = 16*st + l16;
        float mv = 0.f;
        if (ss <= tt) mv = __expf(sSeg[par][tt] - sSeg[par][ss]) * sDt[par][ss] * g[st][r];
        sM[tt][ss] = f2bf(mv);
      }
    }
    __syncthreads();
    // ---- phase 2: Y = M@X^T + cum*(C@h^T) + D*X ; h <- P*h + (X^T W)@B ----
    floatx4 yac[4], y2[4];
    #pragma unroll
    for (int pt = 0; pt < 4; pt++){ yac[pt] = (floatx4){0,0,0,0}; y2[pt] = (floatx4){0,0,0,0}; }
    #pragma unroll
    for (int kt = 0; kt < 2; kt++){
      short8 mf = *(const short8*)&sM[16*wv + l16][kt*32 + q*8];
      #pragma unroll
      for (int pt = 0; pt < 4; pt++){
        short8 xf = *(const short8*)&sXT[16*pt + l16][kt*32 + q*8];
        yac[pt] = __builtin_amdgcn_mfma_f32_16x16x32_bf16(mf, xf, yac[pt], 0, 0, 0);
      }
    }
    #pragma unroll
    for (int kt = 0; kt < 4; kt++){
      #pragma unroll
      for (int pt = 0; pt < 4; pt++){
        short8 hf = *(const short8*)&sH[16*pt + l16][kt*32 + q*8];
        y2[pt] = __builtin_amdgcn_mfma_f32_16x16x32_bf16(cf[kt], hf, y2[pt], 0, 0, 0);
      }
    }
    // state update: wave owns n in [32*wv, 32*wv+32)
    float P = sCum[par][QC-1];
    #pragma unroll
    for (int i = 0; i < 8; i++) hacc[i] *= P;
    #pragma unroll
    for (int kt = 0; kt < 2; kt++){
      short8 bt0, bt1;
      #pragma unroll
      for (int jj = 0; jj < 7; jj++){
        bt0[jj] = (short)sBl[kt*32 + q*8 + jj][32*wv + l16];
        bt1[jj] = (short)sBl[kt*32 + q*8 + jj][32*wv + 16 + l16];
      }
      bt0[7] = (short)sBl[kt*32 + q*8 + 7][32*wv + l16];
      bt1[7] = (short)sBl[kt*32 + q*8 + 7][32*wv + 16 + l16];
      #pragma unroll
      for (int pt = 0; pt < 4; pt++){
        short8 xwf = *(const short8*)&sXW[16*pt + l16][kt*32 + q*8];
        hacc[pt*2+0] = __builtin_amdgcn_mfma_f32_16x16x32_bf16(xwf, bt0, hacc[pt*2+0], 0, 0, 0);
        hacc[pt*2+1] = __builtin_amdgcn_mfma_f32_16x16x32_bf16(xwf, bt1, hacc[pt*2+1], 0, 0, 0);
      }
    }
    // epilogue: y write
    #pragma unroll
    for (int r = 0; r < 4; r++){
      int trow = 16*wv + q*4 + r;
      float cum_t = sCum[par][trow];
      size_t gbase = (size_t)(bseq + l0 + trow)*DINNER + h*HEADD;
      #pragma unroll
      for (int pt = 0; pt < 4; pt++){
        float xv = bf2f(sXT[16*pt + l16][trow]);
        float yv = yac[pt][r] + cum_t * y2[pt][r] + Dh * xv;
        yb[gbase + 16*pt + l16] = f2bf(yv);
      }
    }
    __syncthreads();
    // ---- phase 3: publish h to LDS (bf16) for next chunk's Y_inter ----
    #pragma unroll
    for (int pt = 0; pt < 4; pt++){
      #pragma unroll
      for (int nt = 0; nt < 2; nt++){
        #pragma unroll
        for (int r = 0; r < 4; r++)
          sH[16*pt + q*4 + r][32*wv + 16*nt + l16] = f2bf(hacc[pt*2+nt][r]);
      }
    }
  }
}

// ---------------- gate (silu(z)) + RMSNorm -> yn bf16 ----------------
__global__ __launch_bounds__(256) void gate_rms(const unsigned short* __restrict__ y,
                                                const unsigned short* __restrict__ z,
                                                const float* __restrict__ nw, unsigned short* __restrict__ yn){
  int row = blockIdx.x, t = threadIdx.x;
  const unsigned short* yr = y + (size_t)row*DINNER;
  const unsigned short* zr = z + (size_t)row*DINNER;
  float g[6]; float ss = 0.f;
  #pragma unroll
  for (int i=0;i<6;i++){
    int c2 = t + i*256;
    float zv = bf2f(zr[c2]);
    float gv = bf2f(yr[c2]) * silu(zv);
    g[i] = gv; ss += gv*gv;
  }
  __shared__ float sb_[4];
  #pragma unroll
  for (int o = 32; o > 0; o >>= 1) ss += __shfl_down(ss,o,64);
  if ((t & 63) == 0) sb_[t>>6] = ss;
  __syncthreads();
  ss = sb_[0]+sb_[1]+sb_[2]+sb_[3];
  float scale = rsqrtf(ss*(1.f/DINNER) + 1e-5f);
  unsigned short* ynr = yn + (size_t)row*DINNER;
  #pragma unroll
  for (int i=0;i<6;i++){
    int c2 = t + i*256;
    ynr[c2] = f2bf(g[i]*scale*nw[c2]);
  }
}

extern "C" void kernel_launch(void* const* d_in, const int* in_sizes, int n_in,
                              void* d_out, int out_size, void* d_ws, size_t ws_size,
                              hipStream_t stream){
  const float* x      = (const float*)d_in[0];
  const float* ln_w   = (const float*)d_in[1];
  const float* ln_b   = (const float*)d_in[2];
  const float* W_in   = (const float*)d_in[3];
  const float* conv_w = (const float*)d_in[4];
  const float* conv_b = (const float*)d_in[5];
  const float* A_log  = (const float*)d_in[6];
  const float* Dp     = (const float*)d_in[7];
  const float* dt_b   = (const float*)d_in[8];
  const float* nw     = (const float*)d_in[9];
  const float* W_out  = (const float*)d_in[10];
  float* out = (float*)d_out;

  char* ws = (char*)d_ws;
  size_t off = 0;
  auto alloc = [&](size_t bytes)->char*{ char* pp = ws + off; off += (bytes + 255) & ~(size_t)255; return pp; };
  // total ~198 MB (same footprint class as R2, which fit)
  unsigned short* zbuf  = (unsigned short*)alloc((size_t)ROWS*DINNER*2);   // 50.3 MB
  unsigned short* xbcdt = (unsigned short*)alloc((size_t)ROWS*NXBC*2);     // 62.9 MB
  float* dtraw = (float*)alloc((size_t)ROWS*NH*4);                         // 1.6 MB
  float* dtb   = (float*)alloc((size_t)ROWS*NH*4);                         // 1.6 MB
  char* big0   = alloc((size_t)ROWS*DMODEL*2);                             // 25.2 MB: u_bf then bcconv
  char* big1   = alloc((size_t)NPROJ_PAD*DMODEL*2);                        // 5.3 MB: winT
  unsigned short* ybuf = (unsigned short*)alloc((size_t)ROWS*DINNER*2);    // 50.3 MB
  unsigned short* woutT= (unsigned short*)alloc((size_t)DMODEL*DINNER*2);  // 2.4 MB
  unsigned short* u_bf   = (unsigned short*)big0;   // dead after gemm_in
  unsigned short* bcconv = (unsigned short*)big0;   // ROWS*256*2 = 8.4 MB, born conv_bc
  unsigned short* winT   = (unsigned short*)big1;
  unsigned short* ynb    = xbcdt;                   // born gate_rms (xbcdt dead after ssd)
  (void)ws_size; (void)in_sizes; (void)n_in; (void)out_size;

  transpose_bf16<<<dim3(NPROJ_PAD/32, DMODEL/32), 256, 0, stream>>>(W_in, DMODEL, NPROJ, winT);
  transpose_bf16<<<dim3(DMODEL/32, DINNER/32), 256, 0, stream>>>(W_out, DINNER, DMODEL, woutT);
  ln_kernel<<<ROWS, 256, 0, stream>>>(x, ln_w, ln_b, u_bf);
  gemm_in<<<dim3(NPROJ_PAD/128, ROWS/128), 256, 0, stream>>>((const short*)u_bf, (const short*)winT,
                                                             zbuf, xbcdt, dtraw);
  dt_kernel<<<(ROWS*NH + 255)/256, 256, 0, stream>>>(dtraw, dt_b, dtb);
  conv_bc<<<ROWS, 256, 0, stream>>>(xbcdt, conv_w, conv_b, bcconv);
  ssd_scan<<<B_SZ*NH, 256, 0, stream>>>(xbcdt, bcconv, dtb, conv_w, conv_b, A_log, Dp, ybuf);
  gate_rms<<<ROWS, 256, 0, stream>>>(ybuf, zbuf, nw, ynb);
  gemm_out<<<dim3(DMODEL/128, ROWS/128), 256, 0, stream>>>((const short*)ynb, (const short*)woutT,
                                                           out, x);
}

// Round 4
// 582.780 us; speedup vs baseline: 3.0649x; 1.3342x over previous
//
#include <hip/hip_runtime.h>
#include <stdint.h>

#define B_SZ 4
#define LSEQ 4096
#define DMODEL 768
#define DSTATE 128
#define HEADD 64
#define DINNER 1536
#define NH 24
#define NPROJ 3352
#define NPROJ_PAD 3456
#define NXBC 1920            // xbcdt buffer width = NPROJ_PAD - DINNER
#define ROWS (B_SZ*LSEQ)     // 16384
#define QC 64                // SSD chunk length
#define NGRP 8               // groups per (b,h)
#define GQ 8                 // chunks per group (NGRP*GQ*QC == LSEQ)
#define GLEN (GQ*QC)         // 512

typedef __attribute__((ext_vector_type(8))) short short8;
typedef __attribute__((ext_vector_type(4))) float floatx4;

__device__ __forceinline__ unsigned short f2bf(float f){
  union { float f; unsigned u; } v; v.f = f;
  unsigned r = v.u + 0x7FFFu + ((v.u >> 16) & 1u);
  return (unsigned short)(r >> 16);
}
__device__ __forceinline__ float bf2f(unsigned short u){
  union { unsigned u; float f; } v; v.u = ((unsigned)u) << 16; return v.f;
}
__device__ __forceinline__ float silu(float v){ return v / (1.f + __expf(-v)); }

// ---------------- transpose fp32 src[R][C] -> bf16 dst[n][k]=src[k][n], zero-pad n>=C
__global__ __launch_bounds__(256) void transpose_bf16(const float* __restrict__ src, int R, int C,
                                                      unsigned short* __restrict__ dst){
  __shared__ __align__(16) float tile[32][33];
  int tx = threadIdx.x & 31, ty = threadIdx.x >> 5;   // 32 x 8
  int n0 = blockIdx.x * 32, k0 = blockIdx.y * 32;
  #pragma unroll
  for (int i = 0; i < 4; i++){
    int k = k0 + ty + i*8, n = n0 + tx;
    tile[ty + i*8][tx] = (n < C) ? src[(size_t)k * C + n] : 0.f;
  }
  __syncthreads();
  #pragma unroll
  for (int i = 0; i < 4; i++){
    int n = n0 + ty + i*8, k = k0 + tx;
    dst[(size_t)n * R + k] = f2bf(tile[tx][ty + i*8]);
  }
}

// ---------------- layernorm: x fp32 [ROWS][768] -> u bf16 ----------------
__global__ __launch_bounds__(256) void ln_kernel(const float* __restrict__ x, const float* __restrict__ w,
                                                 const float* __restrict__ b, unsigned short* __restrict__ u){
  int row = blockIdx.x, t = threadIdx.x;
  const float* xr = x + (size_t)row * DMODEL;
  float v0 = xr[t], v1 = xr[t+256], v2 = xr[t+512];
  float s = v0+v1+v2, ss = v0*v0+v1*v1+v2*v2;
  __shared__ float sa[4], sb[4];
  #pragma unroll
  for (int o = 32; o > 0; o >>= 1){ s += __shfl_down(s,o,64); ss += __shfl_down(ss,o,64); }
  if ((t & 63) == 0){ sa[t>>6] = s; sb[t>>6] = ss; }
  __syncthreads();
  s = sa[0]+sa[1]+sa[2]+sa[3]; ss = sb[0]+sb[1]+sb[2]+sb[3];
  float mu = s * (1.f/DMODEL);
  float var = ss * (1.f/DMODEL) - mu*mu;
  float rs = rsqrtf(var + 1e-5f);
  unsigned short* ur = u + (size_t)row * DMODEL;
  ur[t]     = f2bf((v0-mu)*rs*w[t]     + b[t]);
  ur[t+256] = f2bf((v1-mu)*rs*w[t+256] + b[t+256]);
  ur[t+512] = f2bf((v2-mu)*rs*w[t+512] + b[t+512]);
}

// ============ shared MFMA GEMM core (128x128 tile, 4 waves, 16x16x32 bf16) ============
#define SSTR 1040   // LDS seg stride (shorts): 128*8 + 8
#define GEMM_CORE(A_, Bt_, K_)                                                          \
  __shared__ __align__(16) short As[4*SSTR];                                            \
  __shared__ __align__(16) short Bs[4*SSTR];                                            \
  int t = threadIdx.x;                                                                  \
  int bm = blockIdx.y, bn = blockIdx.x;                                                 \
  int wave = t >> 6, lane = t & 63;                                                     \
  int wr = wave >> 1, wc = wave & 1;                                                    \
  int q = lane >> 4, m16 = lane & 15;                                                   \
  floatx4 acc[4][4];                                                                    \
  _Pragma("unroll") for (int i=0;i<4;i++)                                               \
    _Pragma("unroll") for (int j=0;j<4;j++) acc[i][j] = (floatx4){0.f,0.f,0.f,0.f};     \
  const int r0 = t >> 2, s0 = t & 3;                                                    \
  for (int kt = 0; kt < (K_); kt += 32){                                                \
    uint4 av0 = *(const uint4*)((A_)  + (size_t)(bm*128 + r0     )*(K_) + kt + s0*8);   \
    uint4 av1 = *(const uint4*)((A_)  + (size_t)(bm*128 + r0 + 64)*(K_) + kt + s0*8);   \
    uint4 bv0 = *(const uint4*)((Bt_) + (size_t)(bn*128 + r0     )*(K_) + kt + s0*8);   \
    uint4 bv1 = *(const uint4*)((Bt_) + (size_t)(bn*128 + r0 + 64)*(K_) + kt + s0*8);   \
    *(uint4*)(As + s0*SSTR + r0*8)      = av0;                                          \
    *(uint4*)(As + s0*SSTR + (r0+64)*8) = av1;                                          \
    *(uint4*)(Bs + s0*SSTR + r0*8)      = bv0;                                          \
    *(uint4*)(Bs + s0*SSTR + (r0+64)*8) = bv1;                                          \
    __syncthreads();                                                                    \
    short8 af[4], bf_[4];                                                               \
    _Pragma("unroll") for (int i=0;i<4;i++){                                            \
      af[i]  = *(const short8*)(As + q*SSTR + (wr*64 + i*16 + m16)*8);                  \
      bf_[i] = *(const short8*)(Bs + q*SSTR + (wc*64 + i*16 + m16)*8);                  \
    }                                                                                   \
    _Pragma("unroll") for (int i=0;i<4;i++)                                             \
      _Pragma("unroll") for (int j=0;j<4;j++)                                           \
        acc[i][j] = __builtin_amdgcn_mfma_f32_16x16x32_bf16(af[i], bf_[j], acc[i][j], 0, 0, 0); \
    __syncthreads();                                                                    \
  }

// ---------------- GEMM1: u x winT^T -> z bf16, xBC bf16, dtb (softplus fused) --------
__global__ __launch_bounds__(256) void gemm_in(const short* __restrict__ A, const short* __restrict__ Bt,
                                               unsigned short* __restrict__ zb, unsigned short* __restrict__ xb,
                                               float* __restrict__ dtb, const float* __restrict__ dt_bias){
  GEMM_CORE(A, Bt, DMODEL)
  #pragma unroll
  for (int i=0;i<4;i++){
    int grow_base = bm*128 + wr*64 + i*16 + q*4;
    #pragma unroll
    for (int j=0;j<4;j++){
      int gcol = bn*128 + wc*64 + j*16 + m16;
      #pragma unroll
      for (int r=0;r<4;r++){
        int row = grow_base + r;
        float v = acc[i][j][r];
        if (gcol < DINNER){
          zb[(size_t)row*DINNER + gcol] = f2bf(v);
        } else {
          xb[(size_t)row*NXBC + (gcol - DINNER)] = f2bf(v);
          if (gcol >= (NPROJ-NH) && gcol < NPROJ){
            int hh = gcol - (NPROJ-NH);
            float xr = v + dt_bias[hh];
            dtb[(size_t)row*NH + hh] = (xr > 20.f) ? xr : log1pf(expf(xr));
          }
        }
      }
    }
  }
}

// ---------------- GEMM2: generic fp32 out + residual ----------------
__global__ __launch_bounds__(256) void gemm_out(const short* __restrict__ A, const short* __restrict__ Bt,
                                                float* __restrict__ C, const float* __restrict__ resid){
  GEMM_CORE(A, Bt, DINNER)
  #pragma unroll
  for (int i=0;i<4;i++){
    int grow_base = bm*128 + wr*64 + i*16 + q*4;
    #pragma unroll
    for (int j=0;j<4;j++){
      int gcol = bn*128 + wc*64 + j*16 + m16;
      #pragma unroll
      for (int r=0;r<4;r++){
        size_t idx = (size_t)(grow_base + r) * DMODEL + gcol;
        C[idx] = acc[i][j][r] + resid[idx];
      }
    }
  }
}

// ---------------- conv+silu for B,C channels only -> bcconv [ROWS][256] bf16 ---------
__global__ __launch_bounds__(256) void conv_bc(const unsigned short* __restrict__ xbc,
                                               const float* __restrict__ cw, const float* __restrict__ cb,
                                               unsigned short* __restrict__ bcv){
  int row = blockIdx.x, c = threadIdx.x;          // c = 0..255 (B: 0..127, C: 128..255)
  int l = row & (LSEQ-1);
  int chg = DINNER + c;                           // conv channel index
  float acc = cb[chg];
  #pragma unroll
  for (int k = 0; k < 4; k++){
    int ls = l + k - 3;
    if (ls >= 0) acc = fmaf(cw[chg*4+k], bf2f(xbc[(size_t)(row + k - 3)*NXBC + 1536 + c]), acc);
  }
  bcv[(size_t)row*256 + c] = f2bf(silu(acc));
}

// ---------------- SSD pass A: per-group (512 steps) local chain, Y_intra, S_g, gamma --
// grid = (b*NH)*NGRP, 256 threads = 4 waves. LDS 70.4 KB -> 2 blocks/CU.
__global__ __launch_bounds__(256, 2) void ssd_partial(const unsigned short* __restrict__ xbc,
                                                      const unsigned short* __restrict__ bcv,
                                                      const float* __restrict__ dtb,
                                                      const float* __restrict__ cw, const float* __restrict__ cb,
                                                      const float* __restrict__ A_log, const float* __restrict__ Dp,
                                                      unsigned short* __restrict__ yb,
                                                      unsigned short* __restrict__ gstate,
                                                      float* __restrict__ gamma){
  __shared__ __align__(16) unsigned short sBl[QC][136];   // B [s][n] (pad 8)
  __shared__ __align__(16) unsigned short sCl[QC][136];   // C [t][n]
  __shared__ __align__(16) unsigned short sXT[HEADD][72]; // conv'd X^T [p][s]
  __shared__ __align__(16) unsigned short sMR[67*72];     // phase0-1a: raw X rows [67][72]; phase1b-2: M [64][72]
  __shared__ __align__(16) unsigned short sH[HEADD][136]; // local-chain h bf16 [p][n]
  __shared__ float sSeg[QC], sDt[QC], sW[QC], sCum[QC];

  int bid = blockIdx.x;
  int g = bid % NGRP, bh = bid / NGRP;
  int h = bh % NH, b = bh / NH;
  int bseq = b * LSEQ;
  int tid = threadIdx.x;
  int wv = tid >> 6, ln = tid & 63, q = ln >> 4, l16 = ln & 15;
  float A_h = -__expf(A_log[h]);
  float Dh = Dp[h];

  float cwr[4][4], cbr[4];
  #pragma unroll
  for (int sl = 0; sl < 4; sl++){
    int chg = h*HEADD + (tid>>4) + 16*sl;
    #pragma unroll
    for (int k = 0; k < 4; k++) cwr[sl][k] = cw[chg*4+k];
    cbr[sl] = cb[chg];
  }

  for (int i = tid; i < HEADD*136/2; i += 256) ((unsigned*)sH)[i] = 0u;
  floatx4 hacc[8];
  #pragma unroll
  for (int i = 0; i < 8; i++) hacc[i] = (floatx4){0.f,0.f,0.f,0.f};
  float segRun = 0.f;   // wave 0 only

  for (int cc = 0; cc < GQ; cc++){
    int l0 = g*GLEN + cc*QC;
    // ---- phase 0: global loads + LDS staging + seg-scan (wave 0) ----
    {
      int r = tid >> 2, gb = tid & 3;
      const unsigned short* bcrow = bcv + (size_t)(bseq + l0 + r)*256;
      uint4 bcl[8];
      #pragma unroll
      for (int j = 0; j < 8; j++) bcl[j] = *(const uint4*)(bcrow + (gb + 4*j)*8);
      uint4 rxl[3]; int rrow[3], rg[3]; bool rv[3];
      #pragma unroll
      for (int j = 0; j < 3; j++){
        int idx = tid + 256*j;
        rv[j] = idx < 536;                         // 67 rows x 8 groups
        int rr = idx >> 3, gg = idx & 7;
        rrow[j] = rr; rg[j] = gg;
        rxl[j] = (uint4){0,0,0,0};
        if (rv[j]){
          int gl = l0 + rr - 3;
          if (gl >= 0) rxl[j] = *(const uint4*)(xbc + (size_t)(bseq + gl)*NXBC + h*HEADD + gg*8);
        }
      }
      if (wv == 0){
        float dtv = dtb[(size_t)(bseq + l0 + ln)*NH + h];
        float sg = dtv * A_h;
        #pragma unroll
        for (int off = 1; off < 64; off <<= 1){
          float o = __shfl_up(sg, off, 64);
          sg += (ln >= off) ? o : 0.f;
        }
        float segLast = __shfl(sg, 63, 64);
        sSeg[ln] = sg; sDt[ln] = dtv;
        sW[ln] = dtv * __expf(segLast - sg);
        sCum[ln] = __expf(sg);
        gamma[(size_t)bh*LSEQ + l0 + ln] = __expf(segRun + sg);
        segRun += segLast;
      }
      #pragma unroll
      for (int j = 0; j < 8; j++){
        int ch0 = (gb + 4*j) * 8;
        if (ch0 < 128) *(uint4*)&sBl[r][ch0] = bcl[j];
        else           *(uint4*)&sCl[r][ch0-128] = bcl[j];
      }
      #pragma unroll
      for (int j = 0; j < 3; j++)
        if (rv[j]) *(uint4*)&sMR[rrow[j]*72 + rg[j]*8] = rxl[j];
    }
    __syncthreads();   // A: staging visible
    // ---- phase 1a: G MFMAs + X conv (reads sMR raw, writes sXT) ----
    short8 cf[4];
    #pragma unroll
    for (int kt = 0; kt < 4; kt++) cf[kt] = *(const short8*)&sCl[16*wv + l16][kt*32 + q*8];
    floatx4 gacc[4];
    #pragma unroll
    for (int st = 0; st < 4; st++) gacc[st] = (floatx4){0.f,0.f,0.f,0.f};
    #pragma unroll
    for (int kt = 0; kt < 4; kt++){
      #pragma unroll
      for (int st = 0; st < 4; st++){
        short8 bfr = *(const short8*)&sBl[16*st + l16][kt*32 + q*8];
        gacc[st] = __builtin_amdgcn_mfma_f32_16x16x32_bf16(cf[kt], bfr, gacc[st], 0, 0, 0);
      }
    }
    {
      int s4 = (tid & 15) * 4;
      #pragma unroll
      for (int sl = 0; sl < 4; sl++){
        int ch = (tid >> 4) + 16*sl;
        float rr[7];
        #pragma unroll
        for (int k = 0; k < 7; k++) rr[k] = bf2f(sMR[(s4 + k)*72 + ch]);
        #pragma unroll
        for (int i = 0; i < 4; i++){
          float v = cbr[sl] + cwr[sl][0]*rr[i] + cwr[sl][1]*rr[i+1] + cwr[sl][2]*rr[i+2] + cwr[sl][3]*rr[i+3];
          sXT[ch][s4+i] = f2bf(silu(v));
        }
      }
    }
    __syncthreads();   // B: raw X fully consumed
    // ---- phase 1b: M = mask * exp(seg[t]-seg[s]) * dt[s] * G  -> sMR ----
    #pragma unroll
    for (int st = 0; st < 4; st++){
      #pragma unroll
      for (int r = 0; r < 4; r++){
        int tt = 16*wv + q*4 + r;
        int ss = 16*st + l16;
        float mv = 0.f;
        if (ss <= tt) mv = __expf(sSeg[tt] - sSeg[ss]) * sDt[ss] * gacc[st][r];
        sMR[tt*72 + ss] = f2bf(mv);
      }
    }
    __syncthreads();   // C: M visible
    // ---- phase 2: Y = M@X^T + cum*(C@h^T) + D*X ; h <- P*h + (X^T)@(W*B) ----
    short8 xf[2][4];
    #pragma unroll
    for (int kt = 0; kt < 2; kt++)
      #pragma unroll
      for (int pt = 0; pt < 4; pt++)
        xf[kt][pt] = *(const short8*)&sXT[16*pt + l16][kt*32 + q*8];
    floatx4 yac[4], y2[4];
    #pragma unroll
    for (int pt = 0; pt < 4; pt++){ yac[pt] = (floatx4){0,0,0,0}; y2[pt] = (floatx4){0,0,0,0}; }
    #pragma unroll
    for (int kt = 0; kt < 2; kt++){
      short8 mf = *(const short8*)&sMR[(16*wv + l16)*72 + kt*32 + q*8];
      #pragma unroll
      for (int pt = 0; pt < 4; pt++)
        yac[pt] = __builtin_amdgcn_mfma_f32_16x16x32_bf16(mf, xf[kt][pt], yac[pt], 0, 0, 0);
    }
    #pragma unroll
    for (int kt = 0; kt < 4; kt++){
      #pragma unroll
      for (int pt = 0; pt < 4; pt++){
        short8 hf = *(const short8*)&sH[16*pt + l16][kt*32 + q*8];
        y2[pt] = __builtin_amdgcn_mfma_f32_16x16x32_bf16(cf[kt], hf, y2[pt], 0, 0, 0);
      }
    }
    float P = sCum[QC-1];
    #pragma unroll
    for (int i = 0; i < 8; i++) hacc[i] *= P;
    #pragma unroll
    for (int kt = 0; kt < 2; kt++){
      float4 w0 = *(const float4*)&sW[kt*32 + q*8];
      float4 w1 = *(const float4*)&sW[kt*32 + q*8 + 4];
      float wsc[8] = { w0.x, w0.y, w0.z, w0.w, w1.x, w1.y, w1.z, w1.w };
      short8 bt0, bt1;
      #pragma unroll
      for (int jj = 0; jj < 8; jj++){
        int srow = kt*32 + q*8 + jj;
        bt0[jj] = (short)f2bf(bf2f(sBl[srow][32*wv + l16])      * wsc[jj]);
        bt1[jj] = (short)f2bf(bf2f(sBl[srow][32*wv + 16 + l16]) * wsc[jj]);
      }
      #pragma unroll
      for (int pt = 0; pt < 4; pt++){
        hacc[pt*2+0] = __builtin_amdgcn_mfma_f32_16x16x32_bf16(xf[kt][pt], bt0, hacc[pt*2+0], 0, 0, 0);
        hacc[pt*2+1] = __builtin_amdgcn_mfma_f32_16x16x32_bf16(xf[kt][pt], bt1, hacc[pt*2+1], 0, 0, 0);
      }
    }
    #pragma unroll
    for (int r = 0; r < 4; r++){
      int trow = 16*wv + q*4 + r;
      float cum_t = sCum[trow];
      size_t gbase = (size_t)(bseq + l0 + trow)*DINNER + h*HEADD;
      #pragma unroll
      for (int pt = 0; pt < 4; pt++){
        float xv = bf2f(sXT[16*pt + l16][trow]);
        yb[gbase + 16*pt + l16] = f2bf(yac[pt][r] + cum_t * y2[pt][r] + Dh * xv);
      }
    }
    __syncthreads();   // D: phase-2 reads done
    // ---- phase 3: publish h to LDS for next chunk ----
    #pragma unroll
    for (int pt = 0; pt < 4; pt++)
      #pragma unroll
      for (int nt = 0; nt < 2; nt++)
        #pragma unroll
        for (int r = 0; r < 4; r++)
          sH[16*pt + q*4 + r][32*wv + 16*nt + l16] = f2bf(hacc[pt*2+nt][r]);
  }
  // group state S_g out (bf16)
  #pragma unroll
  for (int pt = 0; pt < 4; pt++)
    #pragma unroll
    for (int nt = 0; nt < 2; nt++)
      #pragma unroll
      for (int r = 0; r < 4; r++)
        gstate[(size_t)bid*8192 + (16*pt + q*4 + r)*128 + 32*wv + 16*nt + l16] = f2bf(hacc[pt*2+nt][r]);
}

// ---------------- SSD pass B: sequential group combine -> h_init per group ----------
__global__ __launch_bounds__(512) void combine_groups(unsigned short* __restrict__ gstate,
                                                      const float* __restrict__ gamma){
  int bh = blockIdx.x;
  int t = threadIdx.x;
  size_t off = (size_t)(t >> 3)*128 + (t & 7)*16;
  float hr[16];
  #pragma unroll
  for (int i = 0; i < 16; i++) hr[i] = 0.f;
  for (int g = 0; g < NGRP; g++){
    unsigned short* ptr = gstate + (size_t)(bh*NGRP + g)*8192 + off;
    union { uint4 v; unsigned short s[8]; } a0, a1, b0, b1;
    a0.v = *(const uint4*)ptr; a1.v = *(const uint4*)(ptr + 8);
    float P = gamma[(size_t)bh*LSEQ + g*GLEN + (GLEN-1)];
    #pragma unroll
    for (int i = 0; i < 8; i++){ b0.s[i] = f2bf(hr[i]); b1.s[i] = f2bf(hr[8+i]); }
    *(uint4*)ptr = b0.v; *(uint4*)(ptr + 8) = b1.v;    // overwrite with h_init
    #pragma unroll
    for (int i = 0; i < 8; i++){
      hr[i]   = fmaf(P, hr[i],   bf2f(a0.s[i]));
      hr[8+i] = fmaf(P, hr[8+i], bf2f(a1.s[i]));
    }
  }
}

// ---------------- SSD pass C: Y += gamma_t * (C_t @ h_init_g^T)  (MFMA, RMW) ---------
__global__ __launch_bounds__(256) void ssd_fixup(const unsigned short* __restrict__ bcv,
                                                 const unsigned short* __restrict__ gstate,
                                                 const float* __restrict__ gamma,
                                                 unsigned short* __restrict__ yb){
  __shared__ __align__(16) unsigned short sHf[HEADD][136];
  int bid = blockIdx.x;
  int g = bid % NGRP, bh = bid / NGRP;
  int h = bh % NH, b = bh / NH;
  int bseq = b * LSEQ;
  int tid = threadIdx.x, wv = tid >> 6, ln = tid & 63, q = ln >> 4, l16 = ln & 15;
  {
    int p = tid >> 2, n0 = (tid & 3) * 32;
    const unsigned short* src = gstate + (size_t)bid*8192 + p*128 + n0;
    uint4 v0 = *(const uint4*)(src);     uint4 v1 = *(const uint4*)(src + 8);
    uint4 v2 = *(const uint4*)(src + 16); uint4 v3 = *(const uint4*)(src + 24);
    *(uint4*)&sHf[p][n0]      = v0; *(uint4*)&sHf[p][n0 + 8]  = v1;
    *(uint4*)&sHf[p][n0 + 16] = v2; *(uint4*)&sHf[p][n0 + 24] = v3;
  }
  __syncthreads();
  short8 hf[4][4];
  #pragma unroll
  for (int pt = 0; pt < 4; pt++)
    #pragma unroll
    for (int kt = 0; kt < 4; kt++)
      hf[pt][kt] = *(const short8*)&sHf[16*pt + l16][kt*32 + q*8];
  for (int it = 0; it < 8; it++){
    int lrow = g*GLEN + (it*4 + wv)*16;
    short8 cf2[4];
    #pragma unroll
    for (int kt = 0; kt < 4; kt++)
      cf2[kt] = *(const short8*)(bcv + (size_t)(bseq + lrow + l16)*256 + 128 + kt*32 + q*8);
    floatx4 y2[4];
    #pragma unroll
    for (int pt = 0; pt < 4; pt++) y2[pt] = (floatx4){0,0,0,0};
    #pragma unroll
    for (int kt = 0; kt < 4; kt++)
      #pragma unroll
      for (int pt = 0; pt < 4; pt++)
        y2[pt] = __builtin_amdgcn_mfma_f32_16x16x32_bf16(cf2[kt], hf[pt][kt], y2[pt], 0, 0, 0);
    #pragma unroll
    for (int r = 0; r < 4; r++){
      float gv = gamma[(size_t)bh*LSEQ + lrow + q*4 + r];
      size_t ybase = (size_t)(bseq + lrow + q*4 + r)*DINNER + h*HEADD;
      #pragma unroll
      for (int pt = 0; pt < 4; pt++){
        size_t ci = ybase + 16*pt + l16;
        yb[ci] = f2bf(bf2f(yb[ci]) + gv * y2[pt][r]);
      }
    }
  }
}

// ---------------- gate (silu(z)) + RMSNorm -> yn bf16 ----------------
__global__ __launch_bounds__(256) void gate_rms(const unsigned short* __restrict__ y,
                                                const unsigned short* __restrict__ z,
                                                const float* __restrict__ nw, unsigned short* __restrict__ yn){
  int row = blockIdx.x, t = threadIdx.x;
  const unsigned short* yr = y + (size_t)row*DINNER;
  const unsigned short* zr = z + (size_t)row*DINNER;
  float g[6]; float ss = 0.f;
  #pragma unroll
  for (int i=0;i<6;i++){
    int c2 = t + i*256;
    float zv = bf2f(zr[c2]);
    float gv = bf2f(yr[c2]) * silu(zv);
    g[i] = gv; ss += gv*gv;
  }
  __shared__ float sb_[4];
  #pragma unroll
  for (int o = 32; o > 0; o >>= 1) ss += __shfl_down(ss,o,64);
  if ((t & 63) == 0) sb_[t>>6] = ss;
  __syncthreads();
  ss = sb_[0]+sb_[1]+sb_[2]+sb_[3];
  float scale = rsqrtf(ss*(1.f/DINNER) + 1e-5f);
  unsigned short* ynr = yn + (size_t)row*DINNER;
  #pragma unroll
  for (int i=0;i<6;i++){
    int c2 = t + i*256;
    ynr[c2] = f2bf(g[i]*scale*nw[c2]);
  }
}

extern "C" void kernel_launch(void* const* d_in, const int* in_sizes, int n_in,
                              void* d_out, int out_size, void* d_ws, size_t ws_size,
                              hipStream_t stream){
  const float* x      = (const float*)d_in[0];
  const float* ln_w   = (const float*)d_in[1];
  const float* ln_b   = (const float*)d_in[2];
  const float* W_in   = (const float*)d_in[3];
  const float* conv_w = (const float*)d_in[4];
  const float* conv_b = (const float*)d_in[5];
  const float* A_log  = (const float*)d_in[6];
  const float* Dp     = (const float*)d_in[7];
  const float* dt_b   = (const float*)d_in[8];
  const float* nw     = (const float*)d_in[9];
  const float* W_out  = (const float*)d_in[10];
  float* out = (float*)d_out;

  char* ws = (char*)d_ws;
  size_t off = 0;
  auto alloc = [&](size_t bytes)->char*{ char* pp = ws + off; off += (bytes + 255) & ~(size_t)255; return pp; };
  // total ~207 MB (aliased lifetimes)
  unsigned short* zbuf  = (unsigned short*)alloc((size_t)ROWS*DINNER*2);   // 50.3 MB
  unsigned short* xbcdt = (unsigned short*)alloc((size_t)ROWS*NXBC*2);     // 62.9 MB
  float* dtb   = (float*)alloc((size_t)ROWS*NH*4);                         // 1.6 MB
  float* gamma = (float*)alloc((size_t)B_SZ*NH*LSEQ*4);                    // 1.6 MB
  char* big0   = alloc((size_t)ROWS*DMODEL*2);                             // 25.2 MB: u_bf then bcconv
  char* big1   = alloc((size_t)B_SZ*NH*NGRP*HEADD*DSTATE*2);               // 12.6 MB: winT then gstate
  unsigned short* ybuf = (unsigned short*)alloc((size_t)ROWS*DINNER*2);    // 50.3 MB
  unsigned short* woutT= (unsigned short*)alloc((size_t)DMODEL*DINNER*2);  // 2.4 MB
  unsigned short* u_bf   = (unsigned short*)big0;   // dead after gemm_in
  unsigned short* bcconv = (unsigned short*)big0;   // ROWS*256*2 = 8.4 MB, born conv_bc
  unsigned short* winT   = (unsigned short*)big1;   // 5.3 MB, dead after gemm_in
  unsigned short* gstate = (unsigned short*)big1;   // born ssd_partial
  unsigned short* ynb    = xbcdt;                   // born gate_rms (xbcdt dead after ssd_partial)
  (void)ws_size; (void)in_sizes; (void)n_in; (void)out_size;

  transpose_bf16<<<dim3(NPROJ_PAD/32, DMODEL/32), 256, 0, stream>>>(W_in, DMODEL, NPROJ, winT);
  transpose_bf16<<<dim3(DMODEL/32, DINNER/32), 256, 0, stream>>>(W_out, DINNER, DMODEL, woutT);
  ln_kernel<<<ROWS, 256, 0, stream>>>(x, ln_w, ln_b, u_bf);
  gemm_in<<<dim3(NPROJ_PAD/128, ROWS/128), 256, 0, stream>>>((const short*)u_bf, (const short*)winT,
                                                             zbuf, xbcdt, dtb, dt_b);
  conv_bc<<<ROWS, 256, 0, stream>>>(xbcdt, conv_w, conv_b, bcconv);
  ssd_partial<<<B_SZ*NH*NGRP, 256, 0, stream>>>(xbcdt, bcconv, dtb, conv_w, conv_b,
                                                A_log, Dp, ybuf, gstate, gamma);
  combine_groups<<<B_SZ*NH, 512, 0, stream>>>(gstate, gamma);
  ssd_fixup<<<B_SZ*NH*NGRP, 256, 0, stream>>>(bcconv, gstate, gamma, ybuf);
  gate_rms<<<ROWS, 256, 0, stream>>>(ybuf, zbuf, nw, ynb);
  gemm_out<<<dim3(DMODEL/128, ROWS/128), 256, 0, stream>>>((const short*)ynb, (const short*)woutT,
                                                           out, x);
}